// Round 1
// baseline (221.534 us; speedup 1.0000x reference)
//
#include <hip/hip_runtime.h>
#include <hip/hip_cooperative_groups.h>

#define NUM_USER 100000
#define K_NEIGH 32
#define DIM 64

namespace cg = cooperative_groups;

typedef float floatx2 __attribute__((ext_vector_type(2)));
typedef float floatx4 __attribute__((ext_vector_type(4)));
typedef unsigned int uintx2 __attribute__((ext_vector_type(2)));

__device__ __forceinline__ unsigned int pack_bf16(float a, float b) {
  unsigned int ua = __float_as_uint(a), ub = __float_as_uint(b);
  // round-to-nearest-even to bf16
  unsigned int ra = (ua + 0x7fffu + ((ua >> 16) & 1u)) >> 16;
  unsigned int rb = (ub + 0x7fffu + ((ub >> 16) & 1u)) >> 16;
  return ra | (rb << 16);
}

// ---------------------------------------------------------------------------
// Fused single-launch kernel (cooperative): phase 1 converts fp32 features to
// a packed bf16x2 table in d_ws, grid.sync(), phase 2 does the gather+wsum.
//   - phase 2: 32 lanes per user; lane d2 owns dims {2*d2, 2*d2+1}.
//   - g/w loaded ONCE per user (lane d2 holds slot d2), broadcast via __shfl
//     (width 32) -> 3x fewer VMEM instructions than per-k broadcast loads.
//   - streaming data (features, graph, matrix, out) marked nontemporal so the
//     12.8 MB bf16 table keeps the per-XCD L2.
// ---------------------------------------------------------------------------
__global__ __launch_bounds__(256, 8) void fused_convert_gather_kernel(
    const floatx4* __restrict__ feat4,   // features as float4 (1.6M)
    unsigned int*  __restrict__ table,   // [NUM_USER][32] packed bf16x2
    const int*     __restrict__ graph,   // [NUM_USER][32]
    const float*   __restrict__ matrix,  // [NUM_USER][32]
    floatx2*       __restrict__ out2) {  // [NUM_USER][32] float2
  const int tid    = blockIdx.x * blockDim.x + threadIdx.x;
  const int stride = gridDim.x * blockDim.x;

  // ---- Phase 1: fp32 -> bf16x2 table (streaming) ----
  uintx2* table2 = (uintx2*)table;
  for (int i = tid; i < NUM_USER * DIM / 4; i += stride) {
    floatx4 f = __builtin_nontemporal_load(feat4 + i);
    uintx2 r;
    r.x = pack_bf16(f.x, f.y);
    r.y = pack_bf16(f.z, f.w);
    table2[i] = r;  // normal store: keep/writeback through cache
  }

  cg::this_grid().sync();

  // ---- Phase 2: gather + weighted sum ----
  const int total = NUM_USER * 32;
  for (int t = tid; t < total; t += stride) {
    const int u  = t >> 5;   // same for all 32 lanes of a group
    const int d2 = t & 31;

    // one coalesced load each; lane d2 holds neighbor slot d2
    int   myg = __builtin_nontemporal_load(graph  + u * K_NEIGH + d2);
    float myw = __builtin_nontemporal_load(matrix + u * K_NEIGH + d2);

    float acc0 = 0.f, acc1 = 0.f;
#pragma unroll
    for (int k = 0; k < K_NEIGH; ++k) {
      int   idx = __shfl(myg, k, 32);           // broadcast on LDS pipe
      float wk  = __shfl(myw, k, 32);
      unsigned int p = table[idx * 32 + d2];    // 32 lanes x 4B = one 128B line
      acc0 += wk * __uint_as_float(p << 16);          // dim 2*d2
      acc1 += wk * __uint_as_float(p & 0xffff0000u);  // dim 2*d2+1
    }
    floatx2 r; r.x = acc0; r.y = acc1;
    __builtin_nontemporal_store(r, out2 + t);   // 8B/lane coalesced store
  }
}

// ---------------------------------------------------------------------------
// Fallback A (cooperative launch unavailable): previous verified 2-kernel path.
// ---------------------------------------------------------------------------
__global__ __launch_bounds__(256) void convert_bf16_kernel(
    const floatx2* __restrict__ feat2,
    unsigned int*  __restrict__ table) {
  int i = blockIdx.x * blockDim.x + threadIdx.x;
  if (i >= NUM_USER * DIM / 2) return;
  floatx2 f = feat2[i];
  table[i] = pack_bf16(f.x, f.y);
}

__global__ __launch_bounds__(256) void user_graph_gather_bf16_kernel(
    const unsigned int* __restrict__ table,
    const int*          __restrict__ graph,
    const float*        __restrict__ matrix,
    floatx2*            __restrict__ out2) {
  int t  = blockIdx.x * blockDim.x + threadIdx.x;
  int u  = t >> 5;
  int d2 = t & 31;
  if (u >= NUM_USER) return;
  const int*   g = graph  + u * K_NEIGH;
  const float* w = matrix + u * K_NEIGH;
  float acc0 = 0.f, acc1 = 0.f;
#pragma unroll
  for (int k = 0; k < K_NEIGH; ++k) {
    int   idx = g[k];
    float wk  = w[k];
    unsigned int p = table[idx * 32 + d2];
    acc0 += wk * __uint_as_float(p << 16);
    acc1 += wk * __uint_as_float(p & 0xffff0000u);
  }
  floatx2 r; r.x = acc0; r.y = acc1;
  out2[u * 32 + d2] = r;
}

// ---------------------------------------------------------------------------
// Fallback B (no ws space): round-1 fp32 gather, known-good.
// ---------------------------------------------------------------------------
__global__ __launch_bounds__(256) void user_graph_gather_f32_kernel(
    const float* __restrict__ features,
    const int*   __restrict__ graph,
    const float* __restrict__ matrix,
    float*       __restrict__ out) {
  int t = blockIdx.x * blockDim.x + threadIdx.x;
  int u = t >> 6;
  int d = t & 63;
  if (u >= NUM_USER) return;
  const int*   g = graph  + (size_t)u * K_NEIGH;
  const float* w = matrix + (size_t)u * K_NEIGH;
  float acc = 0.f;
#pragma unroll
  for (int k = 0; k < K_NEIGH; ++k)
    acc += w[k] * features[(size_t)g[k] * DIM + d];
  out[(size_t)u * DIM + d] = acc;
}

extern "C" void kernel_launch(void* const* d_in, const int* in_sizes, int n_in,
                              void* d_out, int out_size, void* d_ws, size_t ws_size,
                              hipStream_t stream) {
  const float* features = (const float*)d_in[0];
  const int*   graph    = (const int*)d_in[1];
  const float* matrix   = (const float*)d_in[2];

  const size_t table_bytes = (size_t)NUM_USER * DIM * 2;  // 12.8 MB bf16
  if (ws_size >= table_bytes) {
    unsigned int* table = (unsigned int*)d_ws;

    // Co-resident grid size for the cooperative launch (cached once).
    static int bpc = 0;  // blocks per CU
    if (bpc == 0) {
      int q = 0;
      hipError_t e = hipOccupancyMaxActiveBlocksPerMultiprocessor(
          &q, fused_convert_gather_kernel, 256, 0);
      bpc = (e == hipSuccess && q > 0) ? q : 4;
      if (bpc > 8) bpc = 8;  // 32 waves/CU / 4 waves per 256-thr block
    }
    int nblk = bpc * 256;  // 256 CUs on MI355X

    const floatx4* feat4 = (const floatx4*)features;
    floatx2*       o2    = (floatx2*)d_out;
    void* args[] = {(void*)&feat4, (void*)&table, (void*)&graph,
                    (void*)&matrix, (void*)&o2};
    hipError_t e = hipLaunchCooperativeKernel(
        fused_convert_gather_kernel, dim3(nblk), dim3(256), args, 0, stream);
    if (e == hipSuccess) return;

    // Cooperative launch failed (e.g. capture restriction): verified 2-kernel path.
    (void)hipGetLastError();
    const int n_pack = NUM_USER * DIM / 2;
    convert_bf16_kernel<<<(n_pack + 255) / 256, 256, 0, stream>>>(
        (const floatx2*)features, table);
    const int total = NUM_USER * 32;
    user_graph_gather_bf16_kernel<<<(total + 255) / 256, 256, 0, stream>>>(
        table, graph, matrix, (floatx2*)d_out);
  } else {
    const int total = NUM_USER * DIM;
    user_graph_gather_f32_kernel<<<(total + 255) / 256, 256, 0, stream>>>(
        features, graph, matrix, (float*)d_out);
  }
}

// Round 2
// 216.181 us; speedup vs baseline: 1.0248x; 1.0248x over previous
//
#include <hip/hip_runtime.h>
#include <hip/hip_cooperative_groups.h>

#define NUM_USER 100000
#define K_NEIGH 32
#define DIM 64

namespace cg = cooperative_groups;

typedef float floatx2 __attribute__((ext_vector_type(2)));
typedef float floatx4 __attribute__((ext_vector_type(4)));
typedef unsigned int uintx2 __attribute__((ext_vector_type(2)));

__device__ __forceinline__ unsigned int pack_bf16(float a, float b) {
  unsigned int ua = __float_as_uint(a), ub = __float_as_uint(b);
  // round-to-nearest-even to bf16
  unsigned int ra = (ua + 0x7fffu + ((ua >> 16) & 1u)) >> 16;
  unsigned int rb = (ub + 0x7fffu + ((ub >> 16) & 1u)) >> 16;
  return ra | (rb << 16);
}

// ---------------------------------------------------------------------------
// Fused single-launch cooperative kernel.
//   Phase 1: fp32 features -> packed bf16x2 table in d_ws (grid-stride).
//   grid.sync()
//   Phase 2: EXACT structure of the measured-51us gather kernel:
//     32 lanes/user, lane d2 owns dims {2*d2, 2*d2+1};
//     per-k uniform loads of g[k]/w[k] (L1-hit broadcast, batch-issuable --
//     do NOT replace with shuffles: that adds an lgkmcnt dep in front of
//     every gather and serializes the loop, measured 190us in round 1).
//   launch_bounds(256,4): min 4 waves/SIMD (VGPR cap 128) -- lets the
//   allocator keep a window of outstanding gathers (round 1's (256,8)
//   clamped to 32 VGPRs and killed ILP).
// ---------------------------------------------------------------------------
__global__ __launch_bounds__(256, 4) void fused_convert_gather_kernel(
    const floatx4* __restrict__ feat4,   // features as float4 (1.6M)
    unsigned int*  __restrict__ table,   // [NUM_USER][32] packed bf16x2
    const int*     __restrict__ graph,   // [NUM_USER][32]
    const float*   __restrict__ matrix,  // [NUM_USER][32]
    floatx2*       __restrict__ out2) {  // [NUM_USER][32] float2
  const int tid    = blockIdx.x * blockDim.x + threadIdx.x;
  const int stride = gridDim.x * blockDim.x;

  // ---- Phase 1: fp32 -> bf16x2 table ----
  uintx2* table2 = (uintx2*)table;
  for (int i = tid; i < NUM_USER * DIM / 4; i += stride) {
    floatx4 f = __builtin_nontemporal_load(feat4 + i);  // read-once stream
    uintx2 r;
    r.x = pack_bf16(f.x, f.y);
    r.y = pack_bf16(f.z, f.w);
    table2[i] = r;  // normal store: table is about to be re-read, keep cached
  }

  cg::this_grid().sync();

  // ---- Phase 2: gather + weighted sum (round-0 body, persistent grid) ----
  const int total = NUM_USER * 32;
  for (int t = tid; t < total; t += stride) {
    const int u  = t >> 5;
    const int d2 = t & 31;

    const int*   g = graph  + u * K_NEIGH;
    const float* w = matrix + u * K_NEIGH;

    float acc0 = 0.f, acc1 = 0.f;
#pragma unroll
    for (int k = 0; k < K_NEIGH; ++k) {
      int   idx = g[k];                        // uniform per 32-lane group
      float wk  = w[k];
      unsigned int p = table[idx * 32 + d2];   // 32 lanes x 4B = one 128B line
      acc0 += wk * __uint_as_float(p << 16);          // dim 2*d2
      acc1 += wk * __uint_as_float(p & 0xffff0000u);  // dim 2*d2+1
    }
    floatx2 r; r.x = acc0; r.y = acc1;
    out2[t] = r;                               // 8B/lane coalesced store
  }
}

// ---------------------------------------------------------------------------
// Fallback A (cooperative launch unavailable): verified 2-kernel path (138us).
// ---------------------------------------------------------------------------
__global__ __launch_bounds__(256) void convert_bf16_kernel(
    const floatx2* __restrict__ feat2,
    unsigned int*  __restrict__ table) {
  int i = blockIdx.x * blockDim.x + threadIdx.x;
  if (i >= NUM_USER * DIM / 2) return;
  floatx2 f = feat2[i];
  table[i] = pack_bf16(f.x, f.y);
}

__global__ __launch_bounds__(256) void user_graph_gather_bf16_kernel(
    const unsigned int* __restrict__ table,
    const int*          __restrict__ graph,
    const float*        __restrict__ matrix,
    floatx2*            __restrict__ out2) {
  int t  = blockIdx.x * blockDim.x + threadIdx.x;
  int u  = t >> 5;
  int d2 = t & 31;
  if (u >= NUM_USER) return;
  const int*   g = graph  + u * K_NEIGH;
  const float* w = matrix + u * K_NEIGH;
  float acc0 = 0.f, acc1 = 0.f;
#pragma unroll
  for (int k = 0; k < K_NEIGH; ++k) {
    int   idx = g[k];
    float wk  = w[k];
    unsigned int p = table[idx * 32 + d2];
    acc0 += wk * __uint_as_float(p << 16);
    acc1 += wk * __uint_as_float(p & 0xffff0000u);
  }
  floatx2 r; r.x = acc0; r.y = acc1;
  out2[u * 32 + d2] = r;
}

// ---------------------------------------------------------------------------
// Fallback B (no ws space): round-1 fp32 gather, known-good.
// ---------------------------------------------------------------------------
__global__ __launch_bounds__(256) void user_graph_gather_f32_kernel(
    const float* __restrict__ features,
    const int*   __restrict__ graph,
    const float* __restrict__ matrix,
    float*       __restrict__ out) {
  int t = blockIdx.x * blockDim.x + threadIdx.x;
  int u = t >> 6;
  int d = t & 63;
  if (u >= NUM_USER) return;
  const int*   g = graph  + (size_t)u * K_NEIGH;
  const float* w = matrix + (size_t)u * K_NEIGH;
  float acc = 0.f;
#pragma unroll
  for (int k = 0; k < K_NEIGH; ++k)
    acc += w[k] * features[(size_t)g[k] * DIM + d];
  out[(size_t)u * DIM + d] = acc;
}

extern "C" void kernel_launch(void* const* d_in, const int* in_sizes, int n_in,
                              void* d_out, int out_size, void* d_ws, size_t ws_size,
                              hipStream_t stream) {
  const float* features = (const float*)d_in[0];
  const int*   graph    = (const int*)d_in[1];
  const float* matrix   = (const float*)d_in[2];

  const size_t table_bytes = (size_t)NUM_USER * DIM * 2;  // 12.8 MB bf16
  if (ws_size >= table_bytes) {
    unsigned int* table = (unsigned int*)d_ws;

    // Co-resident grid size for the cooperative launch (cached once).
    static int bpc = 0;  // blocks per CU
    if (bpc == 0) {
      int q = 0;
      hipError_t e = hipOccupancyMaxActiveBlocksPerMultiprocessor(
          &q, fused_convert_gather_kernel, 256, 0);
      bpc = (e == hipSuccess && q > 0) ? q : 4;
      if (bpc > 8) bpc = 8;  // 32 waves/CU cap with 256-thr blocks
    }
    int nblk = bpc * 256;  // 256 CUs on MI355X

    const floatx4* feat4 = (const floatx4*)features;
    floatx2*       o2    = (floatx2*)d_out;
    void* args[] = {(void*)&feat4, (void*)&table, (void*)&graph,
                    (void*)&matrix, (void*)&o2};
    hipError_t e = hipLaunchCooperativeKernel(
        fused_convert_gather_kernel, dim3(nblk), dim3(256), args, 0, stream);
    if (e == hipSuccess) return;

    // Cooperative launch failed: verified 2-kernel path.
    (void)hipGetLastError();
    const int n_pack = NUM_USER * DIM / 2;
    convert_bf16_kernel<<<(n_pack + 255) / 256, 256, 0, stream>>>(
        (const floatx2*)features, table);
    const int total = NUM_USER * 32;
    user_graph_gather_bf16_kernel<<<(total + 255) / 256, 256, 0, stream>>>(
        table, graph, matrix, (floatx2*)d_out);
  } else {
    const int total = NUM_USER * DIM;
    user_graph_gather_f32_kernel<<<(total + 255) / 256, 256, 0, stream>>>(
        features, graph, matrix, (float*)d_out);
  }
}

// Round 3
// 178.774 us; speedup vs baseline: 1.2392x; 1.2092x over previous
//
#include <hip/hip_runtime.h>

#define NUM_USER 100000
#define K_NEIGH 32
#define DIM 64
#define USERS_PER_BLOCK 8   // 256 threads / 32 lanes per user

typedef float floatx2 __attribute__((ext_vector_type(2)));

// ---------------------------------------------------------------------------
// Single-launch f32 gather with LDS-staged {index, weight} pairs.
//
// Lessons encoded from rounds 0-2:
//  * grid.sync() fusion costs ~95us on 2048 blocks (VALU-time accounting,
//    round 2) -> no cooperative launch, no conversion pass, ONE plain launch.
//  * The gather family is L1/TA line-probe bound (bf16 51us vs f32 66us ==
//    96 vs 128 probes/user; 2x instruction & byte deltas don't match).
//    The 64 broadcast g[k]/w[k] VMEM loads per user are 2/3 of the probes ->
//    move them to the LDS pipe (block stages its 8 users' rows once,
//    k-loop uses broadcast ds_read_b64).
//  * Round-1 failure mode (per-k bpermute chain @ 32 VGPRs) avoided:
//    full unroll, no min-waves clamp, LDS reads are batch-issuable.
//  * Wave churn beats persistent grids here -> 1 user-group per thread,
//    12500 blocks, no grid-stride loop.
// ---------------------------------------------------------------------------
__global__ __launch_bounds__(256) void gather_f32_lds_kernel(
    const floatx2* __restrict__ feat2,   // features viewed as float2 [NUM_USER*32]
    const int*     __restrict__ graph,   // [NUM_USER][32]
    const float*   __restrict__ matrix,  // [NUM_USER][32]
    floatx2*       __restrict__ out2) {  // [NUM_USER][32] float2
  __shared__ int2 pairs[USERS_PER_BLOCK * K_NEIGH];  // {idx, w_bits}, 2 KiB

  const int e    = threadIdx.x;                              // 0..255
  const int base = blockIdx.x * (USERS_PER_BLOCK * K_NEIGH); // element offset

  // Stage this block's 8 users' graph+matrix rows: one {idx,w} pair/thread.
  // Nontemporal: read-once streams, keep L2 for the feature table.
  int   gv = __builtin_nontemporal_load(graph  + base + e);
  float wv = __builtin_nontemporal_load(matrix + base + e);
  pairs[e] = make_int2(gv, __float_as_int(wv));
  __syncthreads();

  const int u_local = e >> 5;   // 0..7
  const int d2      = e & 31;   // this lane owns dims {2*d2, 2*d2+1}
  const int u       = blockIdx.x * USERS_PER_BLOCK + u_local;

  const int2* prow = pairs + u_local * K_NEIGH;

  float acc0 = 0.f, acc1 = 0.f;
#pragma unroll
  for (int k = 0; k < K_NEIGH; ++k) {
    int2  pr = prow[k];                       // broadcast ds_read_b64 (LDS pipe)
    float wk = __int_as_float(pr.y);
    floatx2 p = feat2[pr.x * 32 + d2];        // 32 lanes x 8B = 256B/user line
    acc0 += wk * p.x;                         // dim 2*d2
    acc1 += wk * p.y;                         // dim 2*d2+1
  }

  floatx2 r; r.x = acc0; r.y = acc1;
  __builtin_nontemporal_store(r, out2 + u * 32 + d2);  // 8B/lane coalesced
}

extern "C" void kernel_launch(void* const* d_in, const int* in_sizes, int n_in,
                              void* d_out, int out_size, void* d_ws, size_t ws_size,
                              hipStream_t stream) {
  const float* features = (const float*)d_in[0];
  const int*   graph    = (const int*)d_in[1];
  const float* matrix   = (const float*)d_in[2];

  // 100000 users / 8 per block = 12500 blocks exactly; no tail.
  gather_f32_lds_kernel<<<NUM_USER / USERS_PER_BLOCK, 256, 0, stream>>>(
      (const floatx2*)features, graph, matrix, (floatx2*)d_out);
}

// Round 4
// 137.560 us; speedup vs baseline: 1.6105x; 1.2996x over previous
//
#include <hip/hip_runtime.h>

#define NUM_USER 100000
#define K_NEIGH 32
#define DIM 64
#define USERS_PER_BLOCK 8   // 256 threads / 32 lanes per user

typedef float floatx2 __attribute__((ext_vector_type(2)));
typedef float floatx4 __attribute__((ext_vector_type(4)));
typedef unsigned int uintx2 __attribute__((ext_vector_type(2)));

__device__ __forceinline__ unsigned int pack_bf16(float a, float b) {
  unsigned int ua = __float_as_uint(a), ub = __float_as_uint(b);
  // round-to-nearest-even to bf16
  unsigned int ra = (ua + 0x7fffu + ((ua >> 16) & 1u)) >> 16;
  unsigned int rb = (ub + 0x7fffu + ((ub >> 16) & 1u)) >> 16;
  return ra | (rb << 16);
}

// ---------------------------------------------------------------------------
// Session model (rounds 0-3):
//  * Harness overhead is ~76us CONSTANT (not per-launch): r0 63us kernels ->
//    138.6 total; r3 100us kernel -> 178.8 total. Only total kernel time
//    matters; plain multi-launch is fine, grid.sync costs ~95us -> dead.
//  * Gather is TCC-fetch-volume bound: r3 f32 = 349MB @ 3.83TB/s = 91us ~=
//    dispatch; r0 bf16 = 159MB. Fetch scales with table size (L2 capacity
//    misses on a random gather). bf16 table is the right precision.
//  * LDS-staged {idx,w} replaces 64 redundant per-k VMEM broadcasts/user;
//    proven safe in r3 (0 conflicts, no lgkm serialization, VALU 12%).
// This version = bf16 table (r0) + LDS staging (r3).
// ---------------------------------------------------------------------------

// Kernel 1: compress fp32 features -> packed bf16x2 table in d_ws.
// table[u*32 + j] packs dims {2j (low 16), 2j+1 (high 16)}, RNE rounding.
__global__ __launch_bounds__(256) void convert_bf16_kernel(
    const floatx4* __restrict__ feat4,   // 1.6M float4
    uintx2*        __restrict__ table2) {// 1.6M packed bf16x2 pairs
  int i = blockIdx.x * blockDim.x + threadIdx.x;
  if (i >= NUM_USER * DIM / 4) return;
  floatx4 f = __builtin_nontemporal_load(feat4 + i);  // read-once stream
  uintx2 r;
  r.x = pack_bf16(f.x, f.y);
  r.y = pack_bf16(f.z, f.w);
  table2[i] = r;  // normal store: table is re-read next kernel, keep in L2
}

// Kernel 2: gather+weighted-sum from the bf16 table, LDS-staged {idx,w}.
// 32 lanes per user (2 users/wave); lane d2 owns dims {2*d2, 2*d2+1}.
__global__ __launch_bounds__(256) void gather_bf16_lds_kernel(
    const unsigned int* __restrict__ table,   // [NUM_USER][32] bf16x2
    const int*          __restrict__ graph,   // [NUM_USER][32]
    const float*        __restrict__ matrix,  // [NUM_USER][32]
    floatx2*            __restrict__ out2) {  // [NUM_USER][32] float2
  __shared__ int2 pairs[USERS_PER_BLOCK * K_NEIGH];  // {idx, w_bits}, 2 KiB

  const int e    = threadIdx.x;                              // 0..255
  const int base = blockIdx.x * (USERS_PER_BLOCK * K_NEIGH); // elem offset

  // Stage this block's 8 users' graph+matrix rows: one {idx,w} pair/thread.
  int   gv = __builtin_nontemporal_load(graph  + base + e);
  float wv = __builtin_nontemporal_load(matrix + base + e);
  pairs[e] = make_int2(gv, __float_as_int(wv));
  __syncthreads();

  const int u_local = e >> 5;   // 0..7
  const int d2      = e & 31;   // dims {2*d2, 2*d2+1}
  const int2* prow  = pairs + u_local * K_NEIGH;

  float acc0 = 0.f, acc1 = 0.f;
#pragma unroll
  for (int k = 0; k < K_NEIGH; ++k) {
    int2  pr = prow[k];                      // broadcast ds_read_b64, LDS pipe
    float wk = __int_as_float(pr.y);
    unsigned int p = table[pr.x * 32 + d2];  // 32 lanes x 4B = one 128B line
    acc0 += wk * __uint_as_float(p << 16);          // dim 2*d2
    acc1 += wk * __uint_as_float(p & 0xffff0000u);  // dim 2*d2+1
  }
  floatx2 r; r.x = acc0; r.y = acc1;
  // out offset: u*32+d2 = blockIdx*256 + u_local*32 + d2 = base + e
  __builtin_nontemporal_store(r, out2 + base + e);  // 8B/lane coalesced
}

// ---------------------------------------------------------------------------
// Fallback (no ws space): round-3 single-kernel f32 gather, known-good 100us.
// ---------------------------------------------------------------------------
__global__ __launch_bounds__(256) void gather_f32_lds_kernel(
    const floatx2* __restrict__ feat2,
    const int*     __restrict__ graph,
    const float*   __restrict__ matrix,
    floatx2*       __restrict__ out2) {
  __shared__ int2 pairs[USERS_PER_BLOCK * K_NEIGH];
  const int e    = threadIdx.x;
  const int base = blockIdx.x * (USERS_PER_BLOCK * K_NEIGH);
  int   gv = __builtin_nontemporal_load(graph  + base + e);
  float wv = __builtin_nontemporal_load(matrix + base + e);
  pairs[e] = make_int2(gv, __float_as_int(wv));
  __syncthreads();
  const int u_local = e >> 5;
  const int d2      = e & 31;
  const int2* prow  = pairs + u_local * K_NEIGH;
  float acc0 = 0.f, acc1 = 0.f;
#pragma unroll
  for (int k = 0; k < K_NEIGH; ++k) {
    int2  pr = prow[k];
    float wk = __int_as_float(pr.y);
    floatx2 p = feat2[pr.x * 32 + d2];
    acc0 += wk * p.x;
    acc1 += wk * p.y;
  }
  floatx2 r; r.x = acc0; r.y = acc1;
  __builtin_nontemporal_store(r, out2 + base + e);
}

extern "C" void kernel_launch(void* const* d_in, const int* in_sizes, int n_in,
                              void* d_out, int out_size, void* d_ws, size_t ws_size,
                              hipStream_t stream) {
  const float* features = (const float*)d_in[0];
  const int*   graph    = (const int*)d_in[1];
  const float* matrix   = (const float*)d_in[2];

  const size_t table_bytes = (size_t)NUM_USER * DIM * 2;  // 12.8 MB bf16
  if (ws_size >= table_bytes) {
    unsigned int* table = (unsigned int*)d_ws;
    const int n_pack4 = NUM_USER * DIM / 4;  // 1.6M float4 groups
    convert_bf16_kernel<<<(n_pack4 + 255) / 256, 256, 0, stream>>>(
        (const floatx4*)features, (uintx2*)table);
    gather_bf16_lds_kernel<<<NUM_USER / USERS_PER_BLOCK, 256, 0, stream>>>(
        table, graph, matrix, (floatx2*)d_out);
  } else {
    gather_f32_lds_kernel<<<NUM_USER / USERS_PER_BLOCK, 256, 0, stream>>>(
        (const floatx2*)features, graph, matrix, (floatx2*)d_out);
  }
}